// Round 3
// baseline (675.217 us; speedup 1.0000x reference)
//
#include <hip/hip_runtime.h>

typedef __bf16 bf16_t;
typedef __bf16 bf16x8 __attribute__((ext_vector_type(8)));
typedef float floatx4 __attribute__((ext_vector_type(4)));
typedef const __attribute__((address_space(1))) unsigned int* gptr_as1;
typedef __attribute__((address_space(3))) unsigned int* lptr_as3;

#define B_ 8
#define C_ 512
#define L_ 2048
#define D_ 1024
#define H_ 16

// ---------------------------------------------------------------------------
// Transpose + f32->bf16 convert: in (R,C) f32 -> out (C,R) bf16, batched z.
// ---------------------------------------------------------------------------
__global__ __launch_bounds__(256) void _MSA1_ktransf2b(const float* __restrict__ in,
                                                       bf16_t* __restrict__ out,
                                                       int R, int C) {
  size_t zoff = (size_t)blockIdx.z * R * C;
  in += zoff; out += zoff;
  __shared__ bf16_t tile[64][65];
  int r0 = blockIdx.y * 64, c0 = blockIdx.x * 64;
  int t = threadIdx.x;
  #pragma unroll
  for (int i = 0; i < 16; ++i) {
    int idx = t + i * 256;
    int r = idx >> 6, c = idx & 63;
    tile[c][r] = (bf16_t)in[(size_t)(r0 + r) * C + (c0 + c)];
  }
  __syncthreads();
  #pragma unroll
  for (int i = 0; i < 16; ++i) {
    int idx = t + i * 256;
    int r = idx >> 6, c = idx & 63;
    out[(size_t)(c0 + r) * R + (r0 + c)] = tile[r][c];
  }
}

// bf16 -> bf16 transpose, batched z.
__global__ __launch_bounds__(256) void _MSA1_ktransb(const bf16_t* __restrict__ in,
                                                     bf16_t* __restrict__ out,
                                                     int R, int C) {
  size_t zoff = (size_t)blockIdx.z * R * C;
  in += zoff; out += zoff;
  __shared__ bf16_t tile[64][65];
  int r0 = blockIdx.y * 64, c0 = blockIdx.x * 64;
  int t = threadIdx.x;
  #pragma unroll
  for (int i = 0; i < 16; ++i) {
    int idx = t + i * 256;
    int r = idx >> 6, c = idx & 63;
    tile[c][r] = in[(size_t)(r0 + r) * C + (c0 + c)];
  }
  __syncthreads();
  #pragma unroll
  for (int i = 0; i < 16; ++i) {
    int idx = t + i * 256;
    int r = idx >> 6, c = idx & 63;
    out[(size_t)(c0 + r) * R + (r0 + c)] = tile[r][c];
  }
}

// Concatenate bq|bk|bv (f32) into one 3072-element f32 bias vector.
__global__ __launch_bounds__(256) void _MSA1_kbias3(const float* __restrict__ bq,
                                                    const float* __restrict__ bk,
                                                    const float* __restrict__ bv,
                                                    float* __restrict__ out) {
  for (int i = threadIdx.x; i < 1024; i += 256) {
    out[i] = bq[i];
    out[1024 + i] = bk[i];
    out[2048 + i] = bv[i];
  }
}

// ---------------------------------------------------------------------------
// GEMM: out[m][n] = sum_k A[m][k] * Bt[n][k] + bias[m]
//   A  : (M,K) bf16 row-major (k contiguous), z-stride sA
//   Bt : (N,K) bf16 row-major (k contiguous), z-stride sB
//   Cd : (M,N) row-major, bf16 (F32OUT=0) or f32 (F32OUT=1), z-stride sC
// m97 structure: 128x128 tile, BK=32, 4 waves each 64x64, 16x16x32 bf16 MFMA,
// global_load_lds width-16 staging.
// ---------------------------------------------------------------------------
template <bool F32OUT>
__global__ __launch_bounds__(256) void _MSA1_kgemm(
    const bf16_t* __restrict__ A, const bf16_t* __restrict__ Bt,
    const float* __restrict__ bias, void* __restrict__ Cdv,
    int M, int N, int K, long sA, long sB, long sC) {
  A  += (size_t)blockIdx.z * sA;
  Bt += (size_t)blockIdx.z * sB;
  const int m0 = blockIdx.y * 128, n0 = blockIdx.x * 128;

  __shared__ bf16_t As[128][32];     // [m][k], k contiguous
  __shared__ bf16_t Bs[128][32];     // [n][k], k contiguous
  __shared__ bf16_t Ep[128][132];    // epilogue repack (bf16 path), +4 pad

  const int t = threadIdx.x;
  const int lane = t & 63, w = t >> 6;
  const int mh = (w & 1) * 64, nh = (w >> 1) * 64;
  const int fm = lane & 15, fq = lane >> 4;

  floatx4 acc[4][4];
  #pragma unroll
  for (int i = 0; i < 4; ++i)
    #pragma unroll
    for (int j = 0; j < 4; ++j) {
      floatx4 z4 = {0.f, 0.f, 0.f, 0.f};
      acc[i][j] = z4;
    }

  for (int kt = 0; kt < K; kt += 32) {
    __syncthreads();
    // stage 128x32 A-tile and B-tile; 16B/lane, lds dest = wave base + lane*16
    #pragma unroll
    for (int j = 0; j < 2; ++j) {
      int chunk = j * 256 + t;           // == j*256 + w*64 + lane
      int r = chunk >> 2, k8 = (chunk & 3) * 8;
      const bf16_t* ga = A + (size_t)(m0 + r) * K + kt + k8;
      __builtin_amdgcn_global_load_lds((gptr_as1)(const void*)ga,
          (lptr_as3)(void*)((char*)&As[0][0] + j * 4096 + w * 1024), 16, 0, 0);
      const bf16_t* gb = Bt + (size_t)(n0 + r) * K + kt + k8;
      __builtin_amdgcn_global_load_lds((gptr_as1)(const void*)gb,
          (lptr_as3)(void*)((char*)&Bs[0][0] + j * 4096 + w * 1024), 16, 0, 0);
    }
    __syncthreads();

    bf16x8 af[4], bfr[4];
    #pragma unroll
    for (int mt = 0; mt < 4; ++mt)
      af[mt] = *(const bf16x8*)&As[mh + mt * 16 + fm][fq * 8];
    #pragma unroll
    for (int nt = 0; nt < 4; ++nt)
      bfr[nt] = *(const bf16x8*)&Bs[nh + nt * 16 + fm][fq * 8];
    #pragma unroll
    for (int mt = 0; mt < 4; ++mt)
      #pragma unroll
      for (int nt = 0; nt < 4; ++nt)
        acc[mt][nt] = __builtin_amdgcn_mfma_f32_16x16x32_bf16(
            af[mt], bfr[nt], acc[mt][nt], 0, 0, 0);
  }

  // epilogue: C/D frag mapping row(m) = fq*4+reg, col(n) = fm
  if (F32OUT) {
    float* Cd = (float*)Cdv + (size_t)blockIdx.z * sC;
    #pragma unroll
    for (int mt = 0; mt < 4; ++mt) {
      float bv4[4];
      #pragma unroll
      for (int r = 0; r < 4; ++r)
        bv4[r] = bias[m0 + mh + mt * 16 + fq * 4 + r];
      #pragma unroll
      for (int nt = 0; nt < 4; ++nt) {
        int col = n0 + nh + nt * 16 + fm;
        #pragma unroll
        for (int r = 0; r < 4; ++r) {
          int row = m0 + mh + mt * 16 + fq * 4 + r;
          Cd[(size_t)row * N + col] = acc[mt][nt][r] + bv4[r];
        }
      }
    }
  } else {
    bf16_t* Cd = (bf16_t*)Cdv + (size_t)blockIdx.z * sC;
    #pragma unroll
    for (int mt = 0; mt < 4; ++mt) {
      float bv4[4];
      #pragma unroll
      for (int r = 0; r < 4; ++r)
        bv4[r] = bias[m0 + mh + mt * 16 + fq * 4 + r];
      #pragma unroll
      for (int nt = 0; nt < 4; ++nt) {
        int col = nh + nt * 16 + fm;
        #pragma unroll
        for (int r = 0; r < 4; ++r) {
          int row = mh + mt * 16 + fq * 4 + r;
          Ep[row][col] = (bf16_t)(acc[mt][nt][r] + bv4[r]);
        }
      }
    }
    __syncthreads();
    #pragma unroll
    for (int i = 0; i < 16; ++i) {
      int chunk = i * 256 + t;           // 4096 x 8B chunks
      int row = chunk >> 5, c8 = chunk & 31;
      uint2 val = *(const uint2*)&Ep[row][c8 * 4];
      *(uint2*)&Cd[(size_t)(m0 + row) * N + n0 + c8 * 4] = val;
    }
  }
}

// ---------------------------------------------------------------------------
// Attention: qkv (z, 3, D, L) bf16 -> att flat [z][h][l][d] bf16.
// One thread per (z,h,l); all global loads l-contiguous across the wave.
// Window shuffle: g=(h*64+d)*3+w', src channel = g&1023, offset = (g>>10)-1.
// Zero-padded edges participate in softmax with score 0 (faithful).
// ---------------------------------------------------------------------------
__global__ __launch_bounds__(256) void _MSA1_kattn(const bf16_t* __restrict__ qkv,
                                                   bf16_t* __restrict__ att) {
  int l = blockIdx.x * 256 + threadIdx.x;
  int h = blockIdx.y, b = blockIdx.z;
  const bf16_t* base = qkv + (size_t)b * 3 * D_ * L_;
  const bf16_t* qb = base + (size_t)(h * 64) * L_ + l;
  const bf16_t* kb = base + (size_t)D_ * L_;
  const bf16_t* vb = base + (size_t)2 * D_ * L_;

  float qv[64];
  #pragma unroll
  for (int d = 0; d < 64; ++d) qv[d] = (float)qb[(size_t)d * L_];

  const int gb0 = h * 192;
  float s[3];
  #pragma unroll
  for (int wdw = 0; wdw < 3; ++wdw) {
    float acc = 0.f;
    #pragma unroll
    for (int d = 0; d < 64; ++d) {
      int g = gb0 + 3 * d + wdw;
      int c = g & 1023;
      int lp = l + (g >> 10) - 1;
      float kvv = (lp >= 0 && lp < L_) ? (float)kb[(size_t)c * L_ + lp] : 0.f;
      acc += qv[d] * kvv;
    }
    s[wdw] = acc * 0.125f;   // 1/sqrt(64)
  }
  float mx = fmaxf(s[0], fmaxf(s[1], s[2]));
  float e0 = __expf(s[0] - mx), e1 = __expf(s[1] - mx), e2 = __expf(s[2] - mx);
  float inv = 1.f / (e0 + e1 + e2);
  float ee[3] = {e0 * inv, e1 * inv, e2 * inv};

  bf16_t* ob = att + ((size_t)(b * H_ + h) * L_ + l) * 64;
  #pragma unroll
  for (int db = 0; db < 8; ++db) {
    bf16_t o8[8] __attribute__((aligned(16)));
    #pragma unroll
    for (int j = 0; j < 8; ++j) {
      int d = db * 8 + j;
      int g = gb0 + 3 * d;
      float val = 0.f;
      #pragma unroll
      for (int wdw = 0; wdw < 3; ++wdw) {
        int gg = g + wdw;
        int c = gg & 1023;
        int lp = l + (gg >> 10) - 1;
        float vv = (lp >= 0 && lp < L_) ? (float)vb[(size_t)c * L_ + lp] : 0.f;
        val += ee[wdw] * vv;
      }
      o8[j] = (bf16_t)val;
    }
    *(uint4*)(ob + db * 8) = *(const uint4*)o8;
  }
}

// ---------------------------------------------------------------------------
extern "C" void kernel_launch(void* const* d_in, const int* in_sizes, int n_in,
                              void* d_out, int out_size, void* d_ws, size_t ws_size,
                              hipStream_t stream) {
  (void)in_sizes; (void)n_in; (void)out_size;
  const float* x  = (const float*)d_in[0];
  const float* wq = (const float*)d_in[1];
  const float* bq = (const float*)d_in[2];
  const float* wk = (const float*)d_in[3];
  const float* bk = (const float*)d_in[4];
  const float* wv = (const float*)d_in[5];
  const float* bv = (const float*)d_in[6];
  const float* wo = (const float*)d_in[7];
  const float* bo = (const float*)d_in[8];
  float* out = (float*)d_out;
  char* ws = (char*)d_ws;

  // ---- workspace layout (byte offsets, all 16B-aligned) ----
  bf16_t* wT3   = (bf16_t*)(ws);                 // 3x(1024x512) bf16 = 3,145,728 B
  bf16_t* woT   = (bf16_t*)(ws + 3145728);       // (512x1024)  bf16 = 1,048,576 B
  float*  bias3 = (float*) (ws + 4194304);       // 3072 f32 = 12,288 B (pad 16,384)
  const size_t SHARED_END = 4210688;

  // weight prep (shared by both paths)
  _MSA1_kbias3<<<dim3(1), dim3(256), 0, stream>>>(bq, bk, bv, bias3);
  _MSA1_ktransf2b<<<dim3(16, 8, 1), dim3(256), 0, stream>>>(wq, wT3, 512, 1024);
  _MSA1_ktransf2b<<<dim3(16, 8, 1), dim3(256), 0, stream>>>(wk, wT3 + 524288, 512, 1024);
  _MSA1_ktransf2b<<<dim3(16, 8, 1), dim3(256), 0, stream>>>(wv, wT3 + 1048576, 512, 1024);
  _MSA1_ktransf2b<<<dim3(8, 16, 1), dim3(256), 0, stream>>>(wo, woT, 1024, 512);

  // big path byte need: SHARED_END + xT 16,777,216 + qkv 100,663,296
  //                     + att2 33,554,432 + att2T 33,554,432 = 188,760,064 B
  if (ws_size >= 188760064ull) {
    bf16_t* xT    = (bf16_t*)(ws + SHARED_END);
    bf16_t* qkv   = xT + 8388608ull;
    bf16_t* att2  = qkv + 50331648ull;
    bf16_t* att2T = att2 + 16777216ull;

    _MSA1_ktransf2b<<<dim3(32, 8, B_), dim3(256), 0, stream>>>(x, xT, 512, 2048);
    _MSA1_kgemm<false><<<dim3(16, 24, B_), dim3(256), 0, stream>>>(
        wT3, xT, bias3, qkv, 3072, 2048, 512,
        0L, (long)(2048 * 512), (long)(3072 * 2048));
    _MSA1_kattn<<<dim3(8, 16, B_), dim3(256), 0, stream>>>(qkv, att2);
    _MSA1_ktransb<<<dim3(32, 16, B_), dim3(256), 0, stream>>>(att2, att2T, 1024, 2048);
    _MSA1_kgemm<true><<<dim3(16, 4, B_), dim3(256), 0, stream>>>(
        woT, att2T, bo, out, 512, 2048, 1024,
        0L, (long)(2048 * 1024), (long)(512 * 2048));
  } else {
    // per-batch slab path: SHARED_END + 23,068,672 B = 27.3 MB total
    bf16_t* xTb    = (bf16_t*)(ws + SHARED_END);  //  2,097,152 B
    bf16_t* qkvb   = xTb + 1048576ull;            // 12,582,912 B
    bf16_t* att2b  = qkvb + 6291456ull;           //  4,194,304 B
    bf16_t* att2Tb = att2b + 2097152ull;          //  4,194,304 B
    for (int b = 0; b < B_; ++b) {
      const float* xb = x + (size_t)b * C_ * L_;
      _MSA1_ktransf2b<<<dim3(32, 8, 1), dim3(256), 0, stream>>>(xb, xTb, 512, 2048);
      _MSA1_kgemm<false><<<dim3(16, 24, 1), dim3(256), 0, stream>>>(
          wT3, xTb, bias3, qkvb, 3072, 2048, 512, 0L, 0L, 0L);
      _MSA1_kattn<<<dim3(8, 16, 1), dim3(256), 0, stream>>>(qkvb, att2b);
      _MSA1_ktransb<<<dim3(32, 16, 1), dim3(256), 0, stream>>>(att2b, att2Tb, 1024, 2048);
      _MSA1_kgemm<true><<<dim3(16, 4, 1), dim3(256), 0, stream>>>(
          woT, att2Tb, bo, out + (size_t)b * C_ * L_, 512, 2048, 1024, 0L, 0L, 0L);
    }
  }
}

// Round 4
// 332.110 us; speedup vs baseline: 2.0331x; 2.0331x over previous
//
#include <hip/hip_runtime.h>

typedef _Float16 f16_t;
typedef _Float16 f16x2 __attribute__((ext_vector_type(2)));
typedef _Float16 f16x8 __attribute__((ext_vector_type(8)));
typedef float floatx4 __attribute__((ext_vector_type(4)));
typedef unsigned int u32;
typedef const __attribute__((address_space(1))) unsigned int* gptr_as1;
typedef __attribute__((address_space(3))) unsigned int* lptr_as3;

#define B_ 8
#define C_ 512
#define L_ 2048
#define D_ 1024
#define H_ 16

// ---------------------------------------------------------------------------
// Transpose + f32->f16 convert: in (R,C) f32 -> out (C,R) f16, batched z.
// ---------------------------------------------------------------------------
__global__ __launch_bounds__(256) void _MSA1_ktransf2h(const float* __restrict__ in,
                                                       f16_t* __restrict__ out,
                                                       int R, int C) {
  size_t zoff = (size_t)blockIdx.z * R * C;
  in += zoff; out += zoff;
  __shared__ f16_t tile[64][65];
  int r0 = blockIdx.y * 64, c0 = blockIdx.x * 64;
  int t = threadIdx.x;
  #pragma unroll
  for (int i = 0; i < 16; ++i) {
    int idx = t + i * 256;
    int r = idx >> 6, c = idx & 63;
    tile[c][r] = (f16_t)in[(size_t)(r0 + r) * C + (c0 + c)];
  }
  __syncthreads();
  #pragma unroll
  for (int i = 0; i < 16; ++i) {
    int idx = t + i * 256;
    int r = idx >> 6, c = idx & 63;
    out[(size_t)(c0 + r) * R + (r0 + c)] = tile[r][c];
  }
}

// f16 -> f16 transpose, batched z.
__global__ __launch_bounds__(256) void _MSA1_ktransh(const f16_t* __restrict__ in,
                                                     f16_t* __restrict__ out,
                                                     int R, int C) {
  size_t zoff = (size_t)blockIdx.z * R * C;
  in += zoff; out += zoff;
  __shared__ f16_t tile[64][65];
  int r0 = blockIdx.y * 64, c0 = blockIdx.x * 64;
  int t = threadIdx.x;
  #pragma unroll
  for (int i = 0; i < 16; ++i) {
    int idx = t + i * 256;
    int r = idx >> 6, c = idx & 63;
    tile[c][r] = in[(size_t)(r0 + r) * C + (c0 + c)];
  }
  __syncthreads();
  #pragma unroll
  for (int i = 0; i < 16; ++i) {
    int idx = t + i * 256;
    int r = idx >> 6, c = idx & 63;
    out[(size_t)(c0 + r) * R + (r0 + c)] = tile[r][c];
  }
}

// Concatenate bq|bk|bv (f32) into one 3072-element f32 bias vector.
__global__ __launch_bounds__(256) void _MSA1_kbias3(const float* __restrict__ bq,
                                                    const float* __restrict__ bk,
                                                    const float* __restrict__ bv,
                                                    float* __restrict__ out) {
  for (int i = threadIdx.x; i < 1024; i += 256) {
    out[i] = bq[i];
    out[1024 + i] = bk[i];
    out[2048 + i] = bv[i];
  }
}

// ---------------------------------------------------------------------------
// GEMM: out[m][n] = sum_k A[m][k] * Bt[n][k] + bias[m]
//   A  : (M,K) f16 row-major, z-stride sA ; Bt : (N,K) f16 row-major, z-str sB
//   Cd : (M,N) row-major, f16 (F32OUT=0) or f32 (F32OUT=1), z-stride sC
// m97 structure: 128x128 tile, BK=32, 4 waves each 64x64, 16x16x32 f16 MFMA,
// global_load_lds width-16 staging.
// ---------------------------------------------------------------------------
template <bool F32OUT>
__global__ __launch_bounds__(256) void _MSA1_kgemm(
    const f16_t* __restrict__ A, const f16_t* __restrict__ Bt,
    const float* __restrict__ bias, void* __restrict__ Cdv,
    int M, int N, int K, long sA, long sB, long sC) {
  A  += (size_t)blockIdx.z * sA;
  Bt += (size_t)blockIdx.z * sB;
  const int m0 = blockIdx.y * 128, n0 = blockIdx.x * 128;

  __shared__ f16_t As[128][32];
  __shared__ f16_t Bs[128][32];
  __shared__ f16_t Ep[128][132];

  const int t = threadIdx.x;
  const int lane = t & 63, w = t >> 6;
  const int mh = (w & 1) * 64, nh = (w >> 1) * 64;
  const int fm = lane & 15, fq = lane >> 4;

  floatx4 acc[4][4];
  #pragma unroll
  for (int i = 0; i < 4; ++i)
    #pragma unroll
    for (int j = 0; j < 4; ++j) {
      floatx4 z4 = {0.f, 0.f, 0.f, 0.f};
      acc[i][j] = z4;
    }

  for (int kt = 0; kt < K; kt += 32) {
    __syncthreads();
    #pragma unroll
    for (int j = 0; j < 2; ++j) {
      int chunk = j * 256 + t;
      int r = chunk >> 2, k8 = (chunk & 3) * 8;
      const f16_t* ga = A + (size_t)(m0 + r) * K + kt + k8;
      __builtin_amdgcn_global_load_lds((gptr_as1)(const void*)ga,
          (lptr_as3)(void*)((char*)&As[0][0] + j * 4096 + w * 1024), 16, 0, 0);
      const f16_t* gb = Bt + (size_t)(n0 + r) * K + kt + k8;
      __builtin_amdgcn_global_load_lds((gptr_as1)(const void*)gb,
          (lptr_as3)(void*)((char*)&Bs[0][0] + j * 4096 + w * 1024), 16, 0, 0);
    }
    __syncthreads();

    f16x8 af[4], bfr[4];
    #pragma unroll
    for (int mt = 0; mt < 4; ++mt)
      af[mt] = *(const f16x8*)&As[mh + mt * 16 + fm][fq * 8];
    #pragma unroll
    for (int nt = 0; nt < 4; ++nt)
      bfr[nt] = *(const f16x8*)&Bs[nh + nt * 16 + fm][fq * 8];
    #pragma unroll
    for (int mt = 0; mt < 4; ++mt)
      #pragma unroll
      for (int nt = 0; nt < 4; ++nt)
        acc[mt][nt] = __builtin_amdgcn_mfma_f32_16x16x32_f16(
            af[mt], bfr[nt], acc[mt][nt], 0, 0, 0);
  }

  // epilogue: C/D frag mapping row(m) = fq*4+reg, col(n) = fm
  if (F32OUT) {
    float* Cd = (float*)Cdv + (size_t)blockIdx.z * sC;
    #pragma unroll
    for (int mt = 0; mt < 4; ++mt) {
      float bv4[4];
      #pragma unroll
      for (int r = 0; r < 4; ++r)
        bv4[r] = bias[m0 + mh + mt * 16 + fq * 4 + r];
      #pragma unroll
      for (int nt = 0; nt < 4; ++nt) {
        int col = n0 + nh + nt * 16 + fm;
        #pragma unroll
        for (int r = 0; r < 4; ++r) {
          int row = m0 + mh + mt * 16 + fq * 4 + r;
          Cd[(size_t)row * N + col] = acc[mt][nt][r] + bv4[r];
        }
      }
    }
  } else {
    f16_t* Cd = (f16_t*)Cdv + (size_t)blockIdx.z * sC;
    #pragma unroll
    for (int mt = 0; mt < 4; ++mt) {
      float bv4[4];
      #pragma unroll
      for (int r = 0; r < 4; ++r)
        bv4[r] = bias[m0 + mh + mt * 16 + fq * 4 + r];
      #pragma unroll
      for (int nt = 0; nt < 4; ++nt) {
        int col = nh + nt * 16 + fm;
        #pragma unroll
        for (int r = 0; r < 4; ++r) {
          int row = mh + mt * 16 + fq * 4 + r;
          Ep[row][col] = (f16_t)(acc[mt][nt][r] + bv4[r]);
        }
      }
    }
    __syncthreads();
    #pragma unroll
    for (int i = 0; i < 16; ++i) {
      int chunk = i * 256 + t;
      int row = chunk >> 5, c8 = chunk & 31;
      uint2 val = *(const uint2*)&Ep[row][c8 * 4];
      *(uint2*)&Cd[(size_t)(m0 + row) * N + n0 + c8 * 4] = val;
    }
  }
}

// ---------------------------------------------------------------------------
// Attention v2: qkv (z,3,D,L) f16 -> att [z][h][l][d] f16.
// Block: 256 threads = 4 waves, covers 128 l positions (2 per lane, packed
// dword) x all 64 d (16 per wave). Two passes with LDS score reduction.
// All channel/offset math is wave-uniform (readfirstlane) -> SALU.
// l-chunk = blockIdx.x * xmul + xadd (interior/edge grid split).
// ---------------------------------------------------------------------------
template <bool EDGE>
__global__ __launch_bounds__(256) void _MSA1_kattn2(const f16_t* __restrict__ qkv,
                                                    f16_t* __restrict__ att,
                                                    int xmul, int xadd) {
  const int t = threadIdx.x;
  const int lane = t & 63;
  const int wid = __builtin_amdgcn_readfirstlane(t >> 6);
  const int h = blockIdx.y, b = blockIdx.z;
  const int lbase = (blockIdx.x * xmul + xadd) * 128;
  const int l0 = lbase + lane * 2;
  const size_t plane = (size_t)D_ * L_;
  const f16_t* base = qkv + (size_t)b * 3 * plane;

  __shared__ u32 sred[4][3][64];
  __shared__ f16_t tile[128][66];

  // ---- pass 1: partial scores over this wave's 16 d ----
  f16x2 s[3];
  #pragma unroll
  for (int w = 0; w < 3; ++w) { f16x2 z = {(f16_t)0, (f16_t)0}; s[w] = z; }

  const f16_t* qp = base + (size_t)(h * 64 + wid * 16) * L_ + l0;
  const f16_t* kplane = base + plane;
  const int g0 = h * 192 + wid * 48;

  #pragma unroll
  for (int dd = 0; dd < 16; ++dd) {
    u32 qw = *(const u32*)(qp + (size_t)dd * L_);
    f16x2 qv = __builtin_bit_cast(f16x2, qw);
    #pragma unroll
    for (int w = 0; w < 3; ++w) {
      int g = g0 + 3 * dd + w;
      int c = g & 1023;
      int o = (g >> 10) - 1;
      u32 kw = *(const u32*)(kplane + (size_t)c * L_ + (l0 + o));
      if (EDGE) {
        if (o < 0 && l0 == 0) kw &= 0xFFFF0000u;
        if (o > 0 && l0 == 2046) kw &= 0x0000FFFFu;
      }
      s[w] = __builtin_bit_cast(f16x2, kw) * qv + s[w];
    }
  }
  #pragma unroll
  for (int w = 0; w < 3; ++w) sred[wid][w][lane] = __builtin_bit_cast(u32, s[w]);
  __syncthreads();

  // ---- cross-wave reduce + softmax (redundant per wave, per-lane 2 l) ----
  float sl[3], sh[3];
  #pragma unroll
  for (int j = 0; j < 3; ++j) {
    f16x2 a0 = __builtin_bit_cast(f16x2, sred[0][j][lane]);
    f16x2 a1 = __builtin_bit_cast(f16x2, sred[1][j][lane]);
    f16x2 a2 = __builtin_bit_cast(f16x2, sred[2][j][lane]);
    f16x2 a3 = __builtin_bit_cast(f16x2, sred[3][j][lane]);
    f16x2 aa = (a0 + a1) + (a2 + a3);
    sl[j] = (float)aa.x * 0.125f;
    sh[j] = (float)aa.y * 0.125f;
  }
  f16x2 ee[3];
  {
    float mxl = fmaxf(sl[0], fmaxf(sl[1], sl[2]));
    float e0 = __expf(sl[0] - mxl), e1 = __expf(sl[1] - mxl), e2 = __expf(sl[2] - mxl);
    float invl = 1.f / (e0 + e1 + e2);
    float mxh = fmaxf(sh[0], fmaxf(sh[1], sh[2]));
    float f0 = __expf(sh[0] - mxh), f1 = __expf(sh[1] - mxh), f2 = __expf(sh[2] - mxh);
    float invh = 1.f / (f0 + f1 + f2);
    f16x2 t0 = {(f16_t)(e0 * invl), (f16_t)(f0 * invh)}; ee[0] = t0;
    f16x2 t1 = {(f16_t)(e1 * invl), (f16_t)(f1 * invh)}; ee[1] = t1;
    f16x2 t2 = {(f16_t)(e2 * invl), (f16_t)(f2 * invh)}; ee[2] = t2;
  }

  // ---- pass 2: weighted V sum for this wave's 16 d ----
  const f16_t* vplane = base + 2 * plane;
  #pragma unroll
  for (int dd = 0; dd < 16; ++dd) {
    f16x2 acc = {(f16_t)0, (f16_t)0};
    #pragma unroll
    for (int w = 0; w < 3; ++w) {
      int g = g0 + 3 * dd + w;
      int c = g & 1023;
      int o = (g >> 10) - 1;
      u32 vw = *(const u32*)(vplane + (size_t)c * L_ + (l0 + o));
      if (EDGE) {
        if (o < 0 && l0 == 0) vw &= 0xFFFF0000u;
        if (o > 0 && l0 == 2046) vw &= 0x0000FFFFu;
      }
      acc = __builtin_bit_cast(f16x2, vw) * ee[w] + acc;
    }
    int d = wid * 16 + dd;
    tile[lane * 2 + 0][d] = acc.x;
    tile[lane * 2 + 1][d] = acc.y;
  }
  __syncthreads();

  // ---- coalesced store: 128 rows x 128 B ----
  f16_t* ob = att + ((size_t)(b * H_ + h) * L_ + lbase) * 64;
  #pragma unroll
  for (int i = 0; i < 4; ++i) {
    int idx = i * 256 + t;
    int row = idx >> 3, seg = idx & 7;
    const u32* src = (const u32*)&tile[row][seg * 8];
    uint4 val;
    val.x = src[0]; val.y = src[1]; val.z = src[2]; val.w = src[3];
    *(uint4*)(ob + (size_t)row * 64 + seg * 8) = val;
  }
}

// ---------------------------------------------------------------------------
extern "C" void kernel_launch(void* const* d_in, const int* in_sizes, int n_in,
                              void* d_out, int out_size, void* d_ws, size_t ws_size,
                              hipStream_t stream) {
  (void)in_sizes; (void)n_in; (void)out_size;
  const float* x  = (const float*)d_in[0];
  const float* wq = (const float*)d_in[1];
  const float* bq = (const float*)d_in[2];
  const float* wk = (const float*)d_in[3];
  const float* bk = (const float*)d_in[4];
  const float* wv = (const float*)d_in[5];
  const float* bv = (const float*)d_in[6];
  const float* wo = (const float*)d_in[7];
  const float* bo = (const float*)d_in[8];
  float* out = (float*)d_out;
  char* ws = (char*)d_ws;

  // ---- workspace layout (byte offsets) ----
  f16_t* wT3   = (f16_t*)(ws);                 // 3x(1024x512) f16 = 3,145,728 B
  f16_t* woT   = (f16_t*)(ws + 3145728);       // (512x1024)  f16 = 1,048,576 B
  float* bias3 = (float*) (ws + 4194304);      // 3072 f32 (pad to 16,384)
  const size_t SHARED_END = 4210688;

  _MSA1_kbias3<<<dim3(1), dim3(256), 0, stream>>>(bq, bk, bv, bias3);
  _MSA1_ktransf2h<<<dim3(16, 8, 1), dim3(256), 0, stream>>>(wq, wT3, 512, 1024);
  _MSA1_ktransf2h<<<dim3(16, 8, 1), dim3(256), 0, stream>>>(wk, wT3 + 524288, 512, 1024);
  _MSA1_ktransf2h<<<dim3(16, 8, 1), dim3(256), 0, stream>>>(wv, wT3 + 1048576, 512, 1024);
  _MSA1_ktransf2h<<<dim3(8, 16, 1), dim3(256), 0, stream>>>(wo, woT, 1024, 512);

  if (ws_size >= 188760064ull) {
    // ---------- batched-z path ----------
    f16_t* xT    = (f16_t*)(ws + SHARED_END);
    f16_t* qkv   = xT + 8388608ull;
    f16_t* att2  = qkv + 50331648ull;
    f16_t* att2T = att2 + 16777216ull;

    _MSA1_ktransf2h<<<dim3(32, 8, B_), dim3(256), 0, stream>>>(x, xT, 512, 2048);
    _MSA1_kgemm<false><<<dim3(16, 24, B_), dim3(256), 0, stream>>>(
        wT3, xT, bias3, qkv, 3072, 2048, 512,
        0L, (long)(2048 * 512), (long)(3072 * 2048));
    _MSA1_kattn2<false><<<dim3(14, 16, B_), dim3(256), 0, stream>>>(qkv, att2, 1, 1);
    _MSA1_kattn2<true><<<dim3(2, 16, B_), dim3(256), 0, stream>>>(qkv, att2, 15, 0);
    _MSA1_ktransh<<<dim3(32, 16, B_), dim3(256), 0, stream>>>(att2, att2T, 1024, 2048);
    _MSA1_kgemm<true><<<dim3(16, 4, B_), dim3(256), 0, stream>>>(
        woT, att2T, bo, out, 512, 2048, 1024,
        0L, (long)(2048 * 1024), (long)(512 * 2048));
  } else {
    // ---------- per-batch slab path ----------
    f16_t* xTb    = (f16_t*)(ws + SHARED_END);
    f16_t* qkvb   = xTb + 1048576ull;
    f16_t* att2b  = qkvb + 6291456ull;
    f16_t* att2Tb = att2b + 2097152ull;
    for (int b = 0; b < B_; ++b) {
      const float* xb = x + (size_t)b * C_ * L_;
      _MSA1_ktransf2h<<<dim3(32, 8, 1), dim3(256), 0, stream>>>(xb, xTb, 512, 2048);
      _MSA1_kgemm<false><<<dim3(16, 24, 1), dim3(256), 0, stream>>>(
          wT3, xTb, bias3, qkvb, 3072, 2048, 512, 0L, 0L, 0L);
      _MSA1_kattn2<false><<<dim3(14, 16, 1), dim3(256), 0, stream>>>(qkvb, att2b, 1, 1);
      _MSA1_kattn2<true><<<dim3(2, 16, 1), dim3(256), 0, stream>>>(qkvb, att2b, 15, 0);
      _MSA1_ktransh<<<dim3(32, 16, 1), dim3(256), 0, stream>>>(att2b, att2Tb, 1024, 2048);
      _MSA1_kgemm<true><<<dim3(16, 4, 1), dim3(256), 0, stream>>>(
          woT, att2Tb, bo, out + (size_t)b * C_ * L_, 512, 2048, 1024, 0L, 0L, 0L);
    }
  }
}

// Round 5
// 296.706 us; speedup vs baseline: 2.2757x; 1.1193x over previous
//
#include <hip/hip_runtime.h>

typedef _Float16 f16_t;
typedef _Float16 f16x2 __attribute__((ext_vector_type(2)));
typedef _Float16 f16x8 __attribute__((ext_vector_type(8)));
typedef float floatx4 __attribute__((ext_vector_type(4)));
typedef unsigned int u32;
typedef const __attribute__((address_space(1))) unsigned int* gptr_as1;
typedef __attribute__((address_space(3))) unsigned int* lptr_as3;

#define B_ 8
#define C_ 512
#define L_ 2048
#define D_ 1024
#define H_ 16

static __device__ __forceinline__ f16x2 bc2(u32 v) { return __builtin_bit_cast(f16x2, v); }
static __device__ __forceinline__ u32 cb2(f16x2 v) { return __builtin_bit_cast(u32, v); }

// ---------------------------------------------------------------------------
// Transpose + f32->f16 convert: in (R,C) f32 -> out (C,R) f16, batched z.
// ---------------------------------------------------------------------------
__global__ __launch_bounds__(256) void _MSA1_ktransf2h(const float* __restrict__ in,
                                                       f16_t* __restrict__ out,
                                                       int R, int C) {
  size_t zoff = (size_t)blockIdx.z * R * C;
  in += zoff; out += zoff;
  __shared__ f16_t tile[64][65];
  int r0 = blockIdx.y * 64, c0 = blockIdx.x * 64;
  int t = threadIdx.x;
  #pragma unroll
  for (int i = 0; i < 16; ++i) {
    int idx = t + i * 256;
    int r = idx >> 6, c = idx & 63;
    tile[c][r] = (f16_t)in[(size_t)(r0 + r) * C + (c0 + c)];
  }
  __syncthreads();
  #pragma unroll
  for (int i = 0; i < 16; ++i) {
    int idx = t + i * 256;
    int r = idx >> 6, c = idx & 63;
    out[(size_t)(c0 + r) * R + (r0 + c)] = tile[r][c];
  }
}

// f16 -> f16 transpose, batched z.
__global__ __launch_bounds__(256) void _MSA1_ktransh(const f16_t* __restrict__ in,
                                                     f16_t* __restrict__ out,
                                                     int R, int C) {
  size_t zoff = (size_t)blockIdx.z * R * C;
  in += zoff; out += zoff;
  __shared__ f16_t tile[64][65];
  int r0 = blockIdx.y * 64, c0 = blockIdx.x * 64;
  int t = threadIdx.x;
  #pragma unroll
  for (int i = 0; i < 16; ++i) {
    int idx = t + i * 256;
    int r = idx >> 6, c = idx & 63;
    tile[c][r] = in[(size_t)(r0 + r) * C + (c0 + c)];
  }
  __syncthreads();
  #pragma unroll
  for (int i = 0; i < 16; ++i) {
    int idx = t + i * 256;
    int r = idx >> 6, c = idx & 63;
    out[(size_t)(c0 + r) * R + (r0 + c)] = tile[r][c];
  }
}

// Concatenate bq|bk|bv (f32) into one 3072-element f32 bias vector.
__global__ __launch_bounds__(256) void _MSA1_kbias3(const float* __restrict__ bq,
                                                    const float* __restrict__ bk,
                                                    const float* __restrict__ bv,
                                                    float* __restrict__ out) {
  for (int i = threadIdx.x; i < 1024; i += 256) {
    out[i] = bq[i];
    out[1024 + i] = bk[i];
    out[2048 + i] = bv[i];
  }
}

// ---------------------------------------------------------------------------
// GEMM: out[m][n] = sum_k A[m][k] * Bt[n][k] + bias[m]
// m97 structure + (a) LDS union (epilogue aliases staging -> 34KB, 4 blk/CU)
// (b) XOR source-swizzle on staging so frag ds_read_b128 drops 8-way -> 4-way
// bank conflicts. K is a template constant (full unroll, folded addresses).
// ---------------------------------------------------------------------------
template <bool F32OUT, int K>
__global__ __launch_bounds__(256) void _MSA1_kgemm(
    const f16_t* __restrict__ A, const f16_t* __restrict__ Bt,
    const float* __restrict__ bias, void* __restrict__ Cdv,
    int M, int N, long sA, long sB, long sC) {
  A  += (size_t)blockIdx.z * sA;
  Bt += (size_t)blockIdx.z * sB;
  const int m0 = blockIdx.y * 128, n0 = blockIdx.x * 128;

  union ShU {
    struct { f16_t As[128][32]; f16_t Bs[128][32]; } ab;   // 16 KB
    f16_t Ep[F32OUT ? 1 : 128][132];                        // 33.8 KB (bf16 path)
  };
  __shared__ ShU sh;

  const int t = threadIdx.x;
  const int lane = t & 63, w = t >> 6;
  const int mh = (w & 1) * 64, nh = (w >> 1) * 64;
  const int fm = lane & 15, fq = lane >> 4;
  // staging: lane's fixed LDS slot gets the XOR-permuted global k-chunk
  const int srcoff = ((t & 3) ^ ((t >> 2) & 3)) * 8;
  // frag read: logical chunk fq lives at physical column (fq ^ (row&3))
  const int colf = ((fq ^ (fm & 3)) * 8);

  floatx4 acc[4][4];
  #pragma unroll
  for (int i = 0; i < 4; ++i)
    #pragma unroll
    for (int j = 0; j < 4; ++j) {
      floatx4 z4 = {0.f, 0.f, 0.f, 0.f};
      acc[i][j] = z4;
    }

  for (int kt = 0; kt < K; kt += 32) {
    __syncthreads();
    #pragma unroll
    for (int j = 0; j < 2; ++j) {
      int chunk = j * 256 + t;
      int r = chunk >> 2;
      const f16_t* ga = A + (size_t)(m0 + r) * K + kt + srcoff;
      __builtin_amdgcn_global_load_lds((gptr_as1)(const void*)ga,
          (lptr_as3)(void*)((char*)&sh.ab.As[0][0] + j * 4096 + w * 1024), 16, 0, 0);
      const f16_t* gb = Bt + (size_t)(n0 + r) * K + kt + srcoff;
      __builtin_amdgcn_global_load_lds((gptr_as1)(const void*)gb,
          (lptr_as3)(void*)((char*)&sh.ab.Bs[0][0] + j * 4096 + w * 1024), 16, 0, 0);
    }
    __syncthreads();

    f16x8 af[4], bfr[4];
    #pragma unroll
    for (int mt = 0; mt < 4; ++mt)
      af[mt] = *(const f16x8*)&sh.ab.As[mh + mt * 16 + fm][colf];
    #pragma unroll
    for (int nt = 0; nt < 4; ++nt)
      bfr[nt] = *(const f16x8*)&sh.ab.Bs[nh + nt * 16 + fm][colf];
    #pragma unroll
    for (int mt = 0; mt < 4; ++mt)
      #pragma unroll
      for (int nt = 0; nt < 4; ++nt)
        acc[mt][nt] = __builtin_amdgcn_mfma_f32_16x16x32_f16(
            af[mt], bfr[nt], acc[mt][nt], 0, 0, 0);
  }
  __syncthreads();   // Ep aliases As/Bs: all frag reads must drain first

  // epilogue: C/D frag mapping row(m) = fq*4+reg, col(n) = fm
  if (F32OUT) {
    float* Cd = (float*)Cdv + (size_t)blockIdx.z * sC;
    #pragma unroll
    for (int mt = 0; mt < 4; ++mt) {
      float bv4[4];
      #pragma unroll
      for (int r = 0; r < 4; ++r)
        bv4[r] = bias[m0 + mh + mt * 16 + fq * 4 + r];
      #pragma unroll
      for (int nt = 0; nt < 4; ++nt) {
        int col = n0 + nh + nt * 16 + fm;
        #pragma unroll
        for (int r = 0; r < 4; ++r) {
          int row = m0 + mh + mt * 16 + fq * 4 + r;
          Cd[(size_t)row * N + col] = acc[mt][nt][r] + bv4[r];
        }
      }
    }
  } else {
    f16_t* Cd = (f16_t*)Cdv + (size_t)blockIdx.z * sC;
    #pragma unroll
    for (int mt = 0; mt < 4; ++mt) {
      float bv4[4];
      #pragma unroll
      for (int r = 0; r < 4; ++r)
        bv4[r] = bias[m0 + mh + mt * 16 + fq * 4 + r];
      #pragma unroll
      for (int nt = 0; nt < 4; ++nt) {
        int col = nh + nt * 16 + fm;
        #pragma unroll
        for (int r = 0; r < 4; ++r) {
          int row = mh + mt * 16 + fq * 4 + r;
          sh.Ep[row][col] = (f16_t)(acc[mt][nt][r] + bv4[r]);
        }
      }
    }
    __syncthreads();
    #pragma unroll
    for (int i = 0; i < 16; ++i) {
      int chunk = i * 256 + t;
      int row = chunk >> 5, c8 = chunk & 31;
      uint2 val = *(const uint2*)&sh.Ep[row][c8 * 4];
      *(uint2*)&Cd[(size_t)(m0 + row) * N + n0 + c8 * 4] = val;
    }
  }
}

// ---------------------------------------------------------------------------
// Attention v3: 4 l per lane (uint2 loads), block = 4 waves x 16 d, 256 l.
// qkv (z,3,D,L) f16 -> att [z][h][l][d] f16. Grid = exactly 1024 blocks.
// ---------------------------------------------------------------------------
template <bool EDGE>
__global__ __launch_bounds__(256) void _MSA1_kattn3(const f16_t* __restrict__ qkv,
                                                    f16_t* __restrict__ att,
                                                    int xmul, int xadd) {
  const int t = threadIdx.x;
  const int lane = t & 63;
  const int wid = __builtin_amdgcn_readfirstlane(t >> 6);
  const int h = blockIdx.y, b = blockIdx.z;
  const int lbase = (blockIdx.x * xmul + xadd) * 256;
  const int l0 = lbase + lane * 4;
  const size_t plane = (size_t)D_ * L_;
  const f16_t* base = qkv + (size_t)b * 3 * plane;

  __shared__ uint2 sred[4][3][64];
  __shared__ f16_t tile[256][66];

  const f16_t* qp = base + (size_t)(h * 64 + wid * 16) * L_ + l0;
  const f16_t* kpl = base + plane;
  const f16_t* vpl = base + 2 * plane;
  const int g0 = h * 192 + wid * 48;

  // ---- pass 1: partial scores (this wave's 16 d), 4 l per lane ----
  f16x2 sLo[3], sHi[3];
  #pragma unroll
  for (int w = 0; w < 3; ++w) { f16x2 z = {(f16_t)0, (f16_t)0}; sLo[w] = z; sHi[w] = z; }

  #pragma unroll
  for (int dd = 0; dd < 16; ++dd) {
    uint2 qw = *(const uint2*)(qp + (size_t)dd * L_);
    f16x2 qlo = bc2(qw.x), qhi = bc2(qw.y);
    #pragma unroll
    for (int w = 0; w < 3; ++w) {
      int g = g0 + 3 * dd + w;
      int c = g & 1023;
      int o = (g >> 10) - 1;
      uint2 kw = *(const uint2*)(kpl + (size_t)c * L_ + (l0 + o));
      if (EDGE) {
        if (o < 0 && l0 == 0) kw.x &= 0xFFFF0000u;
        if (o > 0 && l0 == 2044) kw.y &= 0x0000FFFFu;
      }
      sLo[w] = bc2(kw.x) * qlo + sLo[w];
      sHi[w] = bc2(kw.y) * qhi + sHi[w];
    }
  }
  #pragma unroll
  for (int w = 0; w < 3; ++w) {
    uint2 v; v.x = cb2(sLo[w]); v.y = cb2(sHi[w]);
    sred[wid][w][lane] = v;
  }
  __syncthreads();

  // ---- cross-wave reduce + softmax (each lane: its own 4 l) ----
  float sc[4][3];
  #pragma unroll
  for (int j = 0; j < 3; ++j) {
    uint2 r0 = sred[0][j][lane], r1 = sred[1][j][lane];
    uint2 r2 = sred[2][j][lane], r3 = sred[3][j][lane];
    f16x2 lo = (bc2(r0.x) + bc2(r1.x)) + (bc2(r2.x) + bc2(r3.x));
    f16x2 hi = (bc2(r0.y) + bc2(r1.y)) + (bc2(r2.y) + bc2(r3.y));
    sc[0][j] = (float)lo.x * 0.125f;
    sc[1][j] = (float)lo.y * 0.125f;
    sc[2][j] = (float)hi.x * 0.125f;
    sc[3][j] = (float)hi.y * 0.125f;
  }
  f16_t ef[4][3];
  #pragma unroll
  for (int li = 0; li < 4; ++li) {
    float mx = fmaxf(sc[li][0], fmaxf(sc[li][1], sc[li][2]));
    float e0 = __expf(sc[li][0] - mx), e1 = __expf(sc[li][1] - mx), e2 = __expf(sc[li][2] - mx);
    float inv = 1.f / (e0 + e1 + e2);
    ef[li][0] = (f16_t)(e0 * inv); ef[li][1] = (f16_t)(e1 * inv); ef[li][2] = (f16_t)(e2 * inv);
  }
  f16x2 eLo[3], eHi[3];
  #pragma unroll
  for (int w = 0; w < 3; ++w) {
    f16x2 a = {ef[0][w], ef[1][w]}; eLo[w] = a;
    f16x2 b2 = {ef[2][w], ef[3][w]}; eHi[w] = b2;
  }

  // ---- pass 2: weighted V sum ----
  #pragma unroll
  for (int dd = 0; dd < 16; ++dd) {
    f16x2 aLo = {(f16_t)0, (f16_t)0}, aHi = {(f16_t)0, (f16_t)0};
    #pragma unroll
    for (int w = 0; w < 3; ++w) {
      int g = g0 + 3 * dd + w;
      int c = g & 1023;
      int o = (g >> 10) - 1;
      uint2 vw = *(const uint2*)(vpl + (size_t)c * L_ + (l0 + o));
      if (EDGE) {
        if (o < 0 && l0 == 0) vw.x &= 0xFFFF0000u;
        if (o > 0 && l0 == 2044) vw.y &= 0x0000FFFFu;
      }
      aLo = bc2(vw.x) * eLo[w] + aLo;
      aHi = bc2(vw.y) * eHi[w] + aHi;
    }
    int d = wid * 16 + dd;
    tile[lane * 4 + 0][d] = aLo.x;
    tile[lane * 4 + 1][d] = aLo.y;
    tile[lane * 4 + 2][d] = aHi.x;
    tile[lane * 4 + 3][d] = aHi.y;
  }
  __syncthreads();

  // ---- coalesced store: 256 rows x 128 B ----
  f16_t* ob = att + ((size_t)(b * H_ + h) * L_ + lbase) * 64;
  #pragma unroll
  for (int i = 0; i < 8; ++i) {
    int idx = i * 256 + t;
    int row = idx >> 3, seg = idx & 7;
    const u32* src = (const u32*)&tile[row][seg * 8];
    uint4 val;
    val.x = src[0]; val.y = src[1]; val.z = src[2]; val.w = src[3];
    *(uint4*)(ob + (size_t)row * 64 + seg * 8) = val;
  }
}

// ---------------------------------------------------------------------------
extern "C" void kernel_launch(void* const* d_in, const int* in_sizes, int n_in,
                              void* d_out, int out_size, void* d_ws, size_t ws_size,
                              hipStream_t stream) {
  (void)in_sizes; (void)n_in; (void)out_size;
  const float* x  = (const float*)d_in[0];
  const float* wq = (const float*)d_in[1];
  const float* bq = (const float*)d_in[2];
  const float* wk = (const float*)d_in[3];
  const float* bk = (const float*)d_in[4];
  const float* wv = (const float*)d_in[5];
  const float* bv = (const float*)d_in[6];
  const float* wo = (const float*)d_in[7];
  const float* bo = (const float*)d_in[8];
  float* out = (float*)d_out;
  char* ws = (char*)d_ws;

  f16_t* wT3   = (f16_t*)(ws);                 // 3x(1024x512) f16 = 3,145,728 B
  f16_t* woT   = (f16_t*)(ws + 3145728);       // (512x1024)  f16 = 1,048,576 B
  float* bias3 = (float*) (ws + 4194304);      // 3072 f32 (pad to 16,384)
  const size_t SHARED_END = 4210688;

  _MSA1_kbias3<<<dim3(1), dim3(256), 0, stream>>>(bq, bk, bv, bias3);
  _MSA1_ktransf2h<<<dim3(16, 8, 1), dim3(256), 0, stream>>>(wq, wT3, 512, 1024);
  _MSA1_ktransf2h<<<dim3(16, 8, 1), dim3(256), 0, stream>>>(wk, wT3 + 524288, 512, 1024);
  _MSA1_ktransf2h<<<dim3(16, 8, 1), dim3(256), 0, stream>>>(wv, wT3 + 1048576, 512, 1024);
  _MSA1_ktransf2h<<<dim3(8, 16, 1), dim3(256), 0, stream>>>(wo, woT, 1024, 512);

  if (ws_size >= 188760064ull) {
    // ---------- batched-z path ----------
    f16_t* xT    = (f16_t*)(ws + SHARED_END);
    f16_t* qkv   = xT + 8388608ull;
    f16_t* att2  = qkv + 50331648ull;
    f16_t* att2T = att2 + 16777216ull;

    _MSA1_ktransf2h<<<dim3(32, 8, B_), dim3(256), 0, stream>>>(x, xT, 512, 2048);
    _MSA1_kgemm<false, 512><<<dim3(16, 24, B_), dim3(256), 0, stream>>>(
        wT3, xT, bias3, qkv, 3072, 2048,
        0L, (long)(2048 * 512), (long)(3072 * 2048));
    _MSA1_kattn3<false><<<dim3(6, 16, B_), dim3(256), 0, stream>>>(qkv, att2, 1, 1);
    _MSA1_kattn3<true><<<dim3(2, 16, B_), dim3(256), 0, stream>>>(qkv, att2, 7, 0);
    _MSA1_ktransh<<<dim3(32, 16, B_), dim3(256), 0, stream>>>(att2, att2T, 1024, 2048);
    _MSA1_kgemm<true, 1024><<<dim3(16, 4, B_), dim3(256), 0, stream>>>(
        woT, att2T, bo, out, 512, 2048,
        0L, (long)(2048 * 1024), (long)(512 * 2048));
  } else {
    // ---------- per-batch slab path ----------
    f16_t* xTb    = (f16_t*)(ws + SHARED_END);
    f16_t* qkvb   = xTb + 1048576ull;
    f16_t* att2b  = qkvb + 6291456ull;
    f16_t* att2Tb = att2b + 2097152ull;
    for (int b = 0; b < B_; ++b) {
      const float* xb = x + (size_t)b * C_ * L_;
      _MSA1_ktransf2h<<<dim3(32, 8, 1), dim3(256), 0, stream>>>(xb, xTb, 512, 2048);
      _MSA1_kgemm<false, 512><<<dim3(16, 24, 1), dim3(256), 0, stream>>>(
          wT3, xTb, bias3, qkvb, 3072, 2048, 0L, 0L, 0L);
      _MSA1_kattn3<false><<<dim3(6, 16, 1), dim3(256), 0, stream>>>(qkvb, att2b, 1, 1);
      _MSA1_kattn3<true><<<dim3(2, 16, 1), dim3(256), 0, stream>>>(qkvb, att2b, 7, 0);
      _MSA1_ktransh<<<dim3(32, 16, 1), dim3(256), 0, stream>>>(att2b, att2Tb, 1024, 2048);
      _MSA1_kgemm<true, 1024><<<dim3(16, 4, 1), dim3(256), 0, stream>>>(
          woT, att2Tb, bo, out + (size_t)b * C_ * L_, 512, 2048, 0L, 0L, 0L);
    }
  }
}

// Round 6
// 283.182 us; speedup vs baseline: 2.3844x; 1.0478x over previous
//
#include <hip/hip_runtime.h>

typedef _Float16 f16_t;
typedef _Float16 f16x2 __attribute__((ext_vector_type(2)));
typedef _Float16 f16x8 __attribute__((ext_vector_type(8)));
typedef float floatx4 __attribute__((ext_vector_type(4)));
typedef unsigned int u32;
typedef const __attribute__((address_space(1))) unsigned int* gptr_as1;
typedef __attribute__((address_space(3))) unsigned int* lptr_as3;

#define B_ 8
#define C_ 512
#define L_ 2048
#define D_ 1024
#define H_ 16

static __device__ __forceinline__ f16x2 bc2(u32 v) { return __builtin_bit_cast(f16x2, v); }
static __device__ __forceinline__ u32 cb2(f16x2 v) { return __builtin_bit_cast(u32, v); }

// ---------------------------------------------------------------------------
// Transpose + f32->f16 convert: in (R,C) f32 -> out (C,R) f16, batched z.
// ---------------------------------------------------------------------------
__global__ __launch_bounds__(256) void _MSA1_ktransf2h(const float* __restrict__ in,
                                                       f16_t* __restrict__ out,
                                                       int R, int C) {
  size_t zoff = (size_t)blockIdx.z * R * C;
  in += zoff; out += zoff;
  __shared__ f16_t tile[64][65];
  int r0 = blockIdx.y * 64, c0 = blockIdx.x * 64;
  int t = threadIdx.x;
  #pragma unroll
  for (int i = 0; i < 16; ++i) {
    int idx = t + i * 256;
    int r = idx >> 6, c = idx & 63;
    tile[c][r] = (f16_t)in[(size_t)(r0 + r) * C + (c0 + c)];
  }
  __syncthreads();
  #pragma unroll
  for (int i = 0; i < 16; ++i) {
    int idx = t + i * 256;
    int r = idx >> 6, c = idx & 63;
    out[(size_t)(c0 + r) * R + (r0 + c)] = tile[r][c];
  }
}

// f16 -> f16 transpose, batched z.
__global__ __launch_bounds__(256) void _MSA1_ktransh(const f16_t* __restrict__ in,
                                                     f16_t* __restrict__ out,
                                                     int R, int C) {
  size_t zoff = (size_t)blockIdx.z * R * C;
  in += zoff; out += zoff;
  __shared__ f16_t tile[64][65];
  int r0 = blockIdx.y * 64, c0 = blockIdx.x * 64;
  int t = threadIdx.x;
  #pragma unroll
  for (int i = 0; i < 16; ++i) {
    int idx = t + i * 256;
    int r = idx >> 6, c = idx & 63;
    tile[c][r] = in[(size_t)(r0 + r) * C + (c0 + c)];
  }
  __syncthreads();
  #pragma unroll
  for (int i = 0; i < 16; ++i) {
    int idx = t + i * 256;
    int r = idx >> 6, c = idx & 63;
    out[(size_t)(c0 + r) * R + (r0 + c)] = tile[r][c];
  }
}

// ---------------------------------------------------------------------------
// Fused prep: all 4 weight transposes (f32->f16) + bias concat, one launch.
// grid (129, 4): y<3,x<128 -> wq/wk/wv (512x1024); y==3,x<128 -> wo (1024x512);
// x==128,y==0 -> bias concat.
// ---------------------------------------------------------------------------
__global__ __launch_bounds__(256) void _MSA1_kprep(
    const float* __restrict__ wq, const float* __restrict__ wk,
    const float* __restrict__ wv, const float* __restrict__ wo,
    const float* __restrict__ bq, const float* __restrict__ bk,
    const float* __restrict__ bv,
    f16_t* __restrict__ wT3, f16_t* __restrict__ woT, float* __restrict__ bias3) {
  const int x = blockIdx.x, y = blockIdx.y;
  const int t = threadIdx.x;
  if (x == 128) {
    if (y == 0) {
      for (int i = t; i < 1024; i += 256) {
        bias3[i] = bq[i];
        bias3[1024 + i] = bk[i];
        bias3[2048 + i] = bv[i];
      }
    }
    return;
  }
  __shared__ f16_t tile[64][65];
  const float* in; f16_t* out; int R, C, r0, c0;
  if (y < 3) {
    R = 512; C = 1024;
    in = (y == 0) ? wq : (y == 1) ? wk : wv;
    out = wT3 + (size_t)y * 524288;
    r0 = (x >> 4) * 64; c0 = (x & 15) * 64;
  } else {
    R = 1024; C = 512;
    in = wo; out = woT;
    r0 = (x >> 3) * 64; c0 = (x & 7) * 64;
  }
  #pragma unroll
  for (int i = 0; i < 16; ++i) {
    int idx = t + i * 256;
    int r = idx >> 6, c = idx & 63;
    tile[c][r] = (f16_t)in[(size_t)(r0 + r) * C + (c0 + c)];
  }
  __syncthreads();
  #pragma unroll
  for (int i = 0; i < 16; ++i) {
    int idx = t + i * 256;
    int r = idx >> 6, c = idx & 63;
    out[(size_t)(c0 + r) * R + (r0 + c)] = tile[r][c];
  }
}

// ---------------------------------------------------------------------------
// GEMM: out[m][n] = sum_k A[m][k] * Bt[n][k] + bias[m]
// 128x128 tile, BK=64 (8 barriers @K=512), 4 waves x 64x64, 16x16x32 f16 MFMA,
// global_load_lds width-16 staging with k-chunk XOR swizzle (phys = log ^
// (row&7)) so BK=64 frag ds_read_b128 keeps the uniform min bank pattern.
// Epilogue LDS aliases staging (union) -> 33.8 KB -> 4 blocks/CU.
// ---------------------------------------------------------------------------
template <bool F32OUT, int K>
__global__ __launch_bounds__(256) void _MSA1_kgemm(
    const f16_t* __restrict__ A, const f16_t* __restrict__ Bt,
    const float* __restrict__ bias, void* __restrict__ Cdv,
    int M, int N, long sA, long sB, long sC) {
  A  += (size_t)blockIdx.z * sA;
  Bt += (size_t)blockIdx.z * sB;
  const int m0 = blockIdx.y * 128, n0 = blockIdx.x * 128;

  union ShU {
    struct { f16_t As[128][64]; f16_t Bs[128][64]; } ab;   // 32 KB
    f16_t Ep[F32OUT ? 1 : 128][132];                        // 33.8 KB (f16 path)
  };
  __shared__ ShU sh;

  const int t = threadIdx.x;
  const int lane = t & 63, w = t >> 6;
  const int mh = (w & 1) * 64, nh = (w >> 1) * 64;
  const int fm = lane & 15, fq = lane >> 4;

  floatx4 acc[4][4];
  #pragma unroll
  for (int i = 0; i < 4; ++i)
    #pragma unroll
    for (int j = 0; j < 4; ++j) {
      floatx4 z4 = {0.f, 0.f, 0.f, 0.f};
      acc[i][j] = z4;
    }

  for (int kt = 0; kt < K; kt += 64) {
    __syncthreads();
    // stage 128x64 A and B tiles; lane slot fixed, global k-chunk XOR-permuted
    #pragma unroll
    for (int j = 0; j < 4; ++j) {
      int c = j * 256 + t;
      int r = c >> 3;
      int k8 = (((c & 7) ^ (r & 7)) * 8);
      const f16_t* ga = A + (size_t)(m0 + r) * K + kt + k8;
      __builtin_amdgcn_global_load_lds((gptr_as1)(const void*)ga,
          (lptr_as3)(void*)((char*)&sh.ab.As[0][0] + j * 4096 + w * 1024), 16, 0, 0);
      const f16_t* gb = Bt + (size_t)(n0 + r) * K + kt + k8;
      __builtin_amdgcn_global_load_lds((gptr_as1)(const void*)gb,
          (lptr_as3)(void*)((char*)&sh.ab.Bs[0][0] + j * 4096 + w * 1024), 16, 0, 0);
    }
    __syncthreads();

    #pragma unroll
    for (int ks = 0; ks < 2; ++ks) {
      f16x8 af[4], bfr[4];
      #pragma unroll
      for (int mt = 0; mt < 4; ++mt) {
        int row = mh + mt * 16 + fm;
        af[mt] = *(const f16x8*)&sh.ab.As[row][(((ks * 4 + fq) ^ (row & 7)) * 8)];
      }
      #pragma unroll
      for (int nt = 0; nt < 4; ++nt) {
        int row = nh + nt * 16 + fm;
        bfr[nt] = *(const f16x8*)&sh.ab.Bs[row][(((ks * 4 + fq) ^ (row & 7)) * 8)];
      }
      #pragma unroll
      for (int mt = 0; mt < 4; ++mt)
        #pragma unroll
        for (int nt = 0; nt < 4; ++nt)
          acc[mt][nt] = __builtin_amdgcn_mfma_f32_16x16x32_f16(
              af[mt], bfr[nt], acc[mt][nt], 0, 0, 0);
    }
  }
  __syncthreads();   // Ep aliases As/Bs: drain frag reads before epilogue

  // epilogue: C/D frag mapping row(m) = fq*4+reg, col(n) = fm
  if (F32OUT) {
    float* Cd = (float*)Cdv + (size_t)blockIdx.z * sC;
    #pragma unroll
    for (int mt = 0; mt < 4; ++mt) {
      float bv4[4];
      #pragma unroll
      for (int r = 0; r < 4; ++r)
        bv4[r] = bias[m0 + mh + mt * 16 + fq * 4 + r];
      #pragma unroll
      for (int nt = 0; nt < 4; ++nt) {
        int col = n0 + nh + nt * 16 + fm;
        #pragma unroll
        for (int r = 0; r < 4; ++r) {
          int row = m0 + mh + mt * 16 + fq * 4 + r;
          Cd[(size_t)row * N + col] = acc[mt][nt][r] + bv4[r];
        }
      }
    }
  } else {
    f16_t* Cd = (f16_t*)Cdv + (size_t)blockIdx.z * sC;
    #pragma unroll
    for (int mt = 0; mt < 4; ++mt) {
      float bv4[4];
      #pragma unroll
      for (int r = 0; r < 4; ++r)
        bv4[r] = bias[m0 + mh + mt * 16 + fq * 4 + r];
      #pragma unroll
      for (int nt = 0; nt < 4; ++nt) {
        int col = nh + nt * 16 + fm;
        #pragma unroll
        for (int r = 0; r < 4; ++r) {
          int row = mh + mt * 16 + fq * 4 + r;
          sh.Ep[row][col] = (f16_t)(acc[mt][nt][r] + bv4[r]);
        }
      }
    }
    __syncthreads();
    #pragma unroll
    for (int i = 0; i < 16; ++i) {
      int chunk = i * 256 + t;
      int row = chunk >> 5, c8 = chunk & 31;
      uint2 val = *(const uint2*)&sh.Ep[row][c8 * 4];
      *(uint2*)&Cd[(size_t)(m0 + row) * N + n0 + c8 * 4] = val;
    }
  }
}

// ---------------------------------------------------------------------------
// Attention v3: 4 l per lane (uint2 loads), block = 4 waves x 16 d, 256 l.
// qkv (z,3,D,L) f16 -> att [z][h][l][d] f16.
// ---------------------------------------------------------------------------
template <bool EDGE>
__global__ __launch_bounds__(256) void _MSA1_kattn3(const f16_t* __restrict__ qkv,
                                                    f16_t* __restrict__ att,
                                                    int xmul, int xadd) {
  const int t = threadIdx.x;
  const int lane = t & 63;
  const int wid = __builtin_amdgcn_readfirstlane(t >> 6);
  const int h = blockIdx.y, b = blockIdx.z;
  const int lbase = (blockIdx.x * xmul + xadd) * 256;
  const int l0 = lbase + lane * 4;
  const size_t plane = (size_t)D_ * L_;
  const f16_t* base = qkv + (size_t)b * 3 * plane;

  __shared__ uint2 sred[4][3][64];
  __shared__ f16_t tile[256][66];

  const f16_t* qp = base + (size_t)(h * 64 + wid * 16) * L_ + l0;
  const f16_t* kpl = base + plane;
  const f16_t* vpl = base + 2 * plane;
  const int g0 = h * 192 + wid * 48;

  // ---- pass 1: partial scores (this wave's 16 d), 4 l per lane ----
  f16x2 sLo[3], sHi[3];
  #pragma unroll
  for (int w = 0; w < 3; ++w) { f16x2 z = {(f16_t)0, (f16_t)0}; sLo[w] = z; sHi[w] = z; }

  #pragma unroll
  for (int dd = 0; dd < 16; ++dd) {
    uint2 qw = *(const uint2*)(qp + (size_t)dd * L_);
    f16x2 qlo = bc2(qw.x), qhi = bc2(qw.y);
    #pragma unroll
    for (int w = 0; w < 3; ++w) {
      int g = g0 + 3 * dd + w;
      int c = g & 1023;
      int o = (g >> 10) - 1;
      uint2 kw = *(const uint2*)(kpl + (size_t)c * L_ + (l0 + o));
      if (EDGE) {
        if (o < 0 && l0 == 0) kw.x &= 0xFFFF0000u;
        if (o > 0 && l0 == 2044) kw.y &= 0x0000FFFFu;
      }
      sLo[w] = bc2(kw.x) * qlo + sLo[w];
      sHi[w] = bc2(kw.y) * qhi + sHi[w];
    }
  }
  #pragma unroll
  for (int w = 0; w < 3; ++w) {
    uint2 v; v.x = cb2(sLo[w]); v.y = cb2(sHi[w]);
    sred[wid][w][lane] = v;
  }
  __syncthreads();

  // ---- cross-wave reduce + softmax (each lane: its own 4 l) ----
  float sc[4][3];
  #pragma unroll
  for (int j = 0; j < 3; ++j) {
    uint2 r0 = sred[0][j][lane], r1 = sred[1][j][lane];
    uint2 r2 = sred[2][j][lane], r3 = sred[3][j][lane];
    f16x2 lo = (bc2(r0.x) + bc2(r1.x)) + (bc2(r2.x) + bc2(r3.x));
    f16x2 hi = (bc2(r0.y) + bc2(r1.y)) + (bc2(r2.y) + bc2(r3.y));
    sc[0][j] = (float)lo.x * 0.125f;
    sc[1][j] = (float)lo.y * 0.125f;
    sc[2][j] = (float)hi.x * 0.125f;
    sc[3][j] = (float)hi.y * 0.125f;
  }
  f16_t ef[4][3];
  #pragma unroll
  for (int li = 0; li < 4; ++li) {
    float mx = fmaxf(sc[li][0], fmaxf(sc[li][1], sc[li][2]));
    float e0 = __expf(sc[li][0] - mx), e1 = __expf(sc[li][1] - mx), e2 = __expf(sc[li][2] - mx);
    float inv = 1.f / (e0 + e1 + e2);
    ef[li][0] = (f16_t)(e0 * inv); ef[li][1] = (f16_t)(e1 * inv); ef[li][2] = (f16_t)(e2 * inv);
  }
  f16x2 eLo[3], eHi[3];
  #pragma unroll
  for (int w = 0; w < 3; ++w) {
    f16x2 a = {ef[0][w], ef[1][w]}; eLo[w] = a;
    f16x2 b2 = {ef[2][w], ef[3][w]}; eHi[w] = b2;
  }

  // ---- pass 2: weighted V sum ----
  #pragma unroll
  for (int dd = 0; dd < 16; ++dd) {
    f16x2 aLo = {(f16_t)0, (f16_t)0}, aHi = {(f16_t)0, (f16_t)0};
    #pragma unroll
    for (int w = 0; w < 3; ++w) {
      int g = g0 + 3 * dd + w;
      int c = g & 1023;
      int o = (g >> 10) - 1;
      uint2 vw = *(const uint2*)(vpl + (size_t)c * L_ + (l0 + o));
      if (EDGE) {
        if (o < 0 && l0 == 0) vw.x &= 0xFFFF0000u;
        if (o > 0 && l0 == 2044) vw.y &= 0x0000FFFFu;
      }
      aLo = bc2(vw.x) * eLo[w] + aLo;
      aHi = bc2(vw.y) * eHi[w] + aHi;
    }
    int d = wid * 16 + dd;
    tile[lane * 4 + 0][d] = aLo.x;
    tile[lane * 4 + 1][d] = aLo.y;
    tile[lane * 4 + 2][d] = aHi.x;
    tile[lane * 4 + 3][d] = aHi.y;
  }
  __syncthreads();

  // ---- coalesced store: 256 rows x 128 B ----
  f16_t* ob = att + ((size_t)(b * H_ + h) * L_ + lbase) * 64;
  #pragma unroll
  for (int i = 0; i < 8; ++i) {
    int idx = i * 256 + t;
    int row = idx >> 3, seg = idx & 7;
    const u32* src = (const u32*)&tile[row][seg * 8];
    uint4 val;
    val.x = src[0]; val.y = src[1]; val.z = src[2]; val.w = src[3];
    *(uint4*)(ob + (size_t)row * 64 + seg * 8) = val;
  }
}

// ---------------------------------------------------------------------------
extern "C" void kernel_launch(void* const* d_in, const int* in_sizes, int n_in,
                              void* d_out, int out_size, void* d_ws, size_t ws_size,
                              hipStream_t stream) {
  (void)in_sizes; (void)n_in; (void)out_size;
  const float* x  = (const float*)d_in[0];
  const float* wq = (const float*)d_in[1];
  const float* bq = (const float*)d_in[2];
  const float* wk = (const float*)d_in[3];
  const float* bk = (const float*)d_in[4];
  const float* wv = (const float*)d_in[5];
  const float* bv = (const float*)d_in[6];
  const float* wo = (const float*)d_in[7];
  const float* bo = (const float*)d_in[8];
  float* out = (float*)d_out;
  char* ws = (char*)d_ws;

  f16_t* wT3   = (f16_t*)(ws);                 // 3x(1024x512) f16 = 3,145,728 B
  f16_t* woT   = (f16_t*)(ws + 3145728);       // (512x1024)  f16 = 1,048,576 B
  float* bias3 = (float*) (ws + 4194304);      // 3072 f32 (pad to 16,384)
  const size_t SHARED_END = 4210688;

  _MSA1_kprep<<<dim3(129, 4), dim3(256), 0, stream>>>(
      wq, wk, wv, wo, bq, bk, bv, wT3, woT, bias3);

  if (ws_size >= 188760064ull) {
    // ---------- batched-z path ----------
    f16_t* xT    = (f16_t*)(ws + SHARED_END);
    f16_t* qkv   = xT + 8388608ull;
    f16_t* att2  = qkv + 50331648ull;
    f16_t* att2T = att2 + 16777216ull;

    _MSA1_ktransf2h<<<dim3(32, 8, B_), dim3(256), 0, stream>>>(x, xT, 512, 2048);
    _MSA1_kgemm<false, 512><<<dim3(16, 24, B_), dim3(256), 0, stream>>>(
        wT3, xT, bias3, qkv, 3072, 2048,
        0L, (long)(2048 * 512), (long)(3072 * 2048));
    _MSA1_kattn3<false><<<dim3(6, 16, B_), dim3(256), 0, stream>>>(qkv, att2, 1, 1);
    _MSA1_kattn3<true><<<dim3(2, 16, B_), dim3(256), 0, stream>>>(qkv, att2, 7, 0);
    _MSA1_ktransh<<<dim3(32, 16, B_), dim3(256), 0, stream>>>(att2, att2T, 1024, 2048);
    _MSA1_kgemm<true, 1024><<<dim3(16, 4, B_), dim3(256), 0, stream>>>(
        woT, att2T, bo, out, 512, 2048,
        0L, (long)(2048 * 1024), (long)(512 * 2048));
  } else {
    // ---------- per-batch slab path ----------
    f16_t* xTb    = (f16_t*)(ws + SHARED_END);
    f16_t* qkvb   = xTb + 1048576ull;
    f16_t* att2b  = qkvb + 6291456ull;
    f16_t* att2Tb = att2b + 2097152ull;
    for (int b = 0; b < B_; ++b) {
      const float* xb = x + (size_t)b * C_ * L_;
      _MSA1_ktransf2h<<<dim3(32, 8, 1), dim3(256), 0, stream>>>(xb, xTb, 512, 2048);
      _MSA1_kgemm<false, 512><<<dim3(16, 24, 1), dim3(256), 0, stream>>>(
          wT3, xTb, bias3, qkvb, 3072, 2048, 0L, 0L, 0L);
      _MSA1_kattn3<false><<<dim3(6, 16, 1), dim3(256), 0, stream>>>(qkvb, att2b, 1, 1);
      _MSA1_kattn3<true><<<dim3(2, 16, 1), dim3(256), 0, stream>>>(qkvb, att2b, 7, 0);
      _MSA1_ktransh<<<dim3(32, 16, 1), dim3(256), 0, stream>>>(att2b, att2Tb, 1024, 2048);
      _MSA1_kgemm<true, 1024><<<dim3(16, 4, 1), dim3(256), 0, stream>>>(
          woT, att2Tb, bo, out + (size_t)b * C_ * L_, 512, 2048, 0L, 0L, 0L);
    }
  }
}